// Round 9
// baseline (162.718 us; speedup 1.0000x reference)
//
#include <hip/hip_runtime.h>
#include <hip/hip_bf16.h>
#include <math.h>

typedef __attribute__((ext_vector_type(8))) short bf16x8_t;
typedef __attribute__((ext_vector_type(4))) int i32x4_t;
typedef __attribute__((ext_vector_type(2))) int i32x2_t;
typedef __attribute__((ext_vector_type(4))) float f32x4_t;
typedef __attribute__((ext_vector_type(16))) float f32x16_t;

#define NH 4
#define HD 16
#define NN 4096
#define CC 64

__device__ __forceinline__ short f2bf(float f) {
  union { float f; unsigned u; } v; v.f = f;
  unsigned r = v.u + 0x7FFFu + ((v.u >> 16) & 1u);
  return (short)(r >> 16);
}

// ---------------- kernel 1: QKV + ts + Kp + ones ----------------
__global__ __launch_bounds__(256) void qkv_kernel(
    const float* __restrict__ x, const float* __restrict__ tpm,
    const float* __restrict__ qkv_w, const float* __restrict__ qkv_b,
    const float* __restrict__ temperature,
    short* __restrict__ Q, short* __restrict__ K, short* __restrict__ Kp,
    short* __restrict__ V, float* __restrict__ ts, short* __restrict__ ones) {
  __shared__ float xs[64][64];  // [c][n] 16 KB
  int bid = blockIdx.x;
  if (bid < 17) {
    int idx = bid * 256 + threadIdx.x;
    if (idx < 4352) ones[idx] = (short)0x3F80;
  }
  int nt = bid % 64;
  int which = (bid / 64) % 3;
  int b = bid / 192;
  int t = threadIdx.x;
  int nl = t & 63;
  int h = __builtin_amdgcn_readfirstlane(t >> 6);  // wave-uniform head
  int n0 = nt * 64;
  int n = n0 + nl;

  {
    int c0 = t >> 6;
    const float* xb = x + ((size_t)b * 64) * NN + n0;
#pragma unroll
    for (int k = 0; k < 16; ++k) {
      int c = c0 + 4 * k;
      xs[c][nl] = xb[(size_t)c * NN + nl];
    }
  }
  __syncthreads();

  int obase = which * 64 + h * 16;
  float acc[16];
#pragma unroll
  for (int d = 0; d < 16; ++d) acc[d] = qkv_b[obase + d];

#pragma unroll 1
  for (int cb = 0; cb < 64; cb += 8) {
    float xr[8];
#pragma unroll
    for (int cc = 0; cc < 8; ++cc) xr[cc] = xs[cb + cc][nl];
#pragma unroll
    for (int d = 0; d < 16; ++d) {
#pragma unroll
      for (int cc = 0; cc < 8; ++cc)
        acc[d] += qkv_w[(obase + d) * 64 + cb + cc] * xr[cc];
    }
  }

  if (which == 2) {
#pragma unroll
    for (int d = 0; d < 16; ++d)
      V[(((size_t)b * NH + h) * HD + d) * NN + n] = f2bf(acc[d]);
    if (h == 0) {
      float tc = temperature[0];
      tc = fminf(fmaxf(tc, 0.1f), 2.0f);
      float tp = tpm[(size_t)b * NN + n];
      tp = fminf(fmaxf(tp, 0.01f), 1.0f);
      ts[(size_t)b * NN + n] = 0.125f * tc * tp * 1.44269504088896341f;
    }
  } else if (which == 0) {
    short pk[16];
#pragma unroll
    for (int d = 0; d < 16; ++d) pk[d] = f2bf(acc[d]);
    short* dst = Q + (((size_t)b * NH + h) * NN + n) * HD;
    *(bf16x8_t*)dst = *(bf16x8_t*)&pk[0];
    *(bf16x8_t*)(dst + 8) = *(bf16x8_t*)&pk[8];
  } else {
    float tc = temperature[0];
    tc = fminf(fmaxf(tc, 0.1f), 2.0f);
    float tp = tpm[(size_t)b * NN + n];
    tp = fminf(fmaxf(tp, 0.01f), 1.0f);
    float tsn = 0.125f * tc * tp * 1.44269504088896341f;
    short pk[16], pkp[16];
#pragma unroll
    for (int d = 0; d < 16; ++d) { pk[d] = f2bf(acc[d]); pkp[d] = f2bf(acc[d] * tsn); }
    short* dst = K + (((size_t)b * NH + h) * NN + n) * HD;
    *(bf16x8_t*)dst = *(bf16x8_t*)&pk[0];
    *(bf16x8_t*)(dst + 8) = *(bf16x8_t*)&pk[8];
    short* dstp = Kp + (((size_t)b * NH + h) * NN + n) * HD;
    *(bf16x8_t*)dstp = *(bf16x8_t*)&pkp[0];
    *(bf16x8_t*)(dstp + 8) = *(bf16x8_t*)&pkp[8];
  }
}

// ---------------- kernel 2: flash attention, swapped-QK^T, all-register P ----------------
__global__ __launch_bounds__(256, 4) void attn_kernel(
    const short* __restrict__ Q, const short* __restrict__ K, const short* __restrict__ Kp,
    const short* __restrict__ V, const short* __restrict__ ones, const float* __restrict__ ts,
    float* __restrict__ OP, float* __restrict__ LP, int jcount) {
  int bid = blockIdx.x;
  int tile = bid & 31;
  int bh = (bid >> 5) & 7;
  int seg = bid >> 8;
  int b = bh >> 2, h = bh & 3;

  int tid = threadIdx.x;
  int w = tid >> 6;
  int lane = tid & 63;
  int half = lane >> 5;
  int l31 = lane & 31;

  int qi0 = tile * 128 + w * 32;
  const short* Qb = Q + (((size_t)b * NH + h) * NN) * HD;
  const short* Kb = K + (((size_t)b * NH + h) * NN) * HD;
  const short* Kpb = Kp + (((size_t)b * NH + h) * NN) * HD;
  const short* Vb = V + (((size_t)b * NH + h) * HD) * NN;

  float tsi = ts[(size_t)b * NN + qi0 + l31];
  bf16x8_t qf = *(const bf16x8_t*)(Qb + (size_t)(qi0 + l31) * HD + 8 * half);

  int jbase = seg * jcount;
  const short* vrow = (l31 < 16) ? (Vb + (size_t)l31 * NN + jbase) : ones;

  f32x16_t acc = {0.f,0.f,0.f,0.f,0.f,0.f,0.f,0.f,0.f,0.f,0.f,0.f,0.f,0.f,0.f,0.f};
  const f32x16_t z16 = {0.f,0.f,0.f,0.f,0.f,0.f,0.f,0.f,0.f,0.f,0.f,0.f,0.f,0.f,0.f,0.f};

#pragma unroll 4
  for (int jj = 0; jj < jcount; jj += 32) {
    const short* kptr = Kb + (size_t)(jbase + jj + l31) * HD + 8 * half;
    const short* kpptr = Kpb + (size_t)(jbase + jj + l31) * HD + 8 * half;
    bf16x8_t ak = *(const bf16x8_t*)kptr;
    bf16x8_t akp = *(const bf16x8_t*)kpptr;
    f32x16_t s = __builtin_amdgcn_mfma_f32_32x32x16_bf16(ak, qf, z16, 0, 0, 0);
    f32x16_t sp = __builtin_amdgcn_mfma_f32_32x32x16_bf16(akp, qf, z16, 0, 0, 0);

    float p[16];
#pragma unroll
    for (int r = 0; r < 16; ++r)
      p[r] = __builtin_amdgcn_exp2f(s[r] * tsi + sp[r]);

    int wr[8];
#pragma unroll
    for (int m = 0; m < 8; ++m)
      asm("v_cvt_pk_bf16_f32 %0, %1, %2" : "=v"(wr[m]) : "v"(p[2 * m]), "v"(p[2 * m + 1]));

    i32x2_t s02 = __builtin_amdgcn_permlane32_swap(wr[0], wr[2], false, false);
    i32x2_t s13 = __builtin_amdgcn_permlane32_swap(wr[1], wr[3], false, false);
    i32x2_t s46 = __builtin_amdgcn_permlane32_swap(wr[4], wr[6], false, false);
    i32x2_t s57 = __builtin_amdgcn_permlane32_swap(wr[5], wr[7], false, false);
    union { i32x4_t i; bf16x8_t b; } pa0, pa1;
    pa0.i = (i32x4_t){s02[0], s13[0], s02[1], s13[1]};
    pa1.i = (i32x4_t){s46[0], s57[0], s46[1], s57[1]};

    bf16x8_t bv0 = *(const bf16x8_t*)(vrow + jj + 8 * half);
    bf16x8_t bv1 = *(const bf16x8_t*)(vrow + jj + 16 + 8 * half);
    acc = __builtin_amdgcn_mfma_f32_32x32x16_bf16(pa0.b, bv0, acc, 0, 0, 0);
    acc = __builtin_amdgcn_mfma_f32_32x32x16_bf16(pa1.b, bv1, acc, 0, 0, 0);
  }

  float* OPb = OP + ((((size_t)seg * 2 + b) * NH + h) * HD) * NN;
  float* LPb = LP + (((size_t)seg * 2 + b) * NH + h) * NN;
  if (l31 < 16) {
#pragma unroll
    for (int g4 = 0; g4 < 4; ++g4) {
      f32x4_t vv = {acc[4 * g4 + 0], acc[4 * g4 + 1], acc[4 * g4 + 2], acc[4 * g4 + 3]};
      *(f32x4_t*)(OPb + (size_t)l31 * NN + qi0 + 4 * half + 8 * g4) = vv;
    }
  } else if (l31 == 16) {
#pragma unroll
    for (int g4 = 0; g4 < 4; ++g4) {
      f32x4_t vv = {acc[4 * g4 + 0], acc[4 * g4 + 1], acc[4 * g4 + 2], acc[4 * g4 + 3]};
      *(f32x4_t*)(LPb + qi0 + 4 * half + 8 * g4) = vv;
    }
  }
}

// ---------------- kernel 3: merge partials + proj (compile-time SK) ----------------
template <int SK>
__global__ __launch_bounds__(256) void proj_kernel_t(
    const float* __restrict__ OP, const float* __restrict__ LP,
    const float* __restrict__ proj_w, const float* __restrict__ proj_b,
    float* __restrict__ out) {
  __shared__ float pv[64][32];
  int bid = blockIdx.x;
  int b = bid >> 7;
  int n0 = (bid & 127) << 5;
  int t = threadIdx.x;
  int nl = t & 31;
  int g = t >> 5;  // 0..7
  int n = n0 + nl;
  int h = g >> 1;

  float lpv[SK];
#pragma unroll
  for (int s = 0; s < SK; ++s)
    lpv[s] = LP[(((size_t)s * 2 + b) * NH + h) * NN + n];
  float opv[8][SK];
#pragma unroll
  for (int cc = 0; cc < 8; ++cc) {
    int d = (g * 8 + cc) & 15;
#pragma unroll
    for (int s = 0; s < SK; ++s)
      opv[cc][s] = OP[((((size_t)s * 2 + b) * NH + h) * HD + d) * NN + n];
  }
  float ls = 0.f;
#pragma unroll
  for (int s = 0; s < SK; ++s) ls += lpv[s];
  float inv = 1.0f / ls;
#pragma unroll
  for (int cc = 0; cc < 8; ++cc) {
    float a = 0.f;
#pragma unroll
    for (int s = 0; s < SK; ++s) a += opv[cc][s];
    pv[g * 8 + cc][nl] = a * inv;
  }
  __syncthreads();

#pragma unroll
  for (int oo = 0; oo < 8; ++oo) {
    int o = g * 8 + oo;
    float a = proj_b[o];
#pragma unroll
    for (int c = 0; c < 64; ++c) a += proj_w[o * 64 + c] * pv[c][nl];
    out[((size_t)b * CC + o) * NN + n] = a;
  }
}

extern "C" void kernel_launch(void* const* d_in, const int* in_sizes, int n_in,
                              void* d_out, int out_size, void* d_ws, size_t ws_size,
                              hipStream_t stream) {
  const float* x = (const float*)d_in[0];
  const float* tpm = (const float*)d_in[1];
  const float* qkv_w = (const float*)d_in[2];
  const float* qkv_b = (const float*)d_in[3];
  const float* proj_w = (const float*)d_in[4];
  const float* proj_b = (const float*)d_in[5];
  const float* temperature = (const float*)d_in[6];
  float* out = (float*)d_out;

  const size_t MB = 1u << 20;
  char* ws = (char*)d_ws;
  short* Q    = (short*)(ws);
  short* K    = (short*)(ws + 1 * MB);
  short* Kp   = (short*)(ws + 2 * MB);
  short* V    = (short*)(ws + 3 * MB);
  float* ts   = (float*)(ws + 4 * MB);            // 32 KB
  short* ones = (short*)(ws + 4 * MB + 32768);    // 16 KB (4352 shorts used)
  size_t lp_off = 4 * MB + 49152;

  int SK = 1;
  for (int cand = 4; cand >= 1; cand >>= 1) {
    size_t need = lp_off + (size_t)cand * (128 * 1024) + (size_t)cand * (2 * MB);
    if (ws_size >= need) { SK = cand; break; }
  }
  float* LP = (float*)(ws + lp_off);
  float* OP = (float*)(ws + lp_off + (size_t)SK * 128 * 1024);

  // ===== R9 measurement round: coprime idempotent duplication =====
  // qkv x2, attn x3, proj x5 — every kernel rewrites identical values, so the
  // output is bit-identical to the single chain. R9 - R8 = q + 2a + 4p + ~7v
  // separates the four "who is slow" hypotheses in one round.
  for (int r = 0; r < 2; ++r)
    qkv_kernel<<<2 * 3 * 64, 256, 0, stream>>>(x, tpm, qkv_w, qkv_b, temperature, Q, K, Kp, V, ts, ones);
  for (int r = 0; r < 3; ++r)
    attn_kernel<<<SK * 256, 256, 0, stream>>>(Q, K, Kp, V, ones, ts, OP, LP, NN / SK);
  for (int r = 0; r < 5; ++r) {
    if (SK == 4)      proj_kernel_t<4><<<2 * 128, 256, 0, stream>>>(OP, LP, proj_w, proj_b, out);
    else if (SK == 2) proj_kernel_t<2><<<2 * 128, 256, 0, stream>>>(OP, LP, proj_w, proj_b, out);
    else              proj_kernel_t<1><<<2 * 128, 256, 0, stream>>>(OP, LP, proj_w, proj_b, out);
  }
}

// Round 11
// 102.147 us; speedup vs baseline: 1.5930x; 1.5930x over previous
//
#include <hip/hip_runtime.h>
#include <hip/hip_bf16.h>
#include <math.h>

typedef __attribute__((ext_vector_type(8))) short bf16x8_t;
typedef __attribute__((ext_vector_type(4))) short short4_t;
typedef __attribute__((ext_vector_type(4))) int i32x4_t;
typedef __attribute__((ext_vector_type(4))) float f32x4_t;

#define NH 4
#define HD 16
#define NN 4096
#define CC 64

__device__ __forceinline__ short f2bf(float f) {
  union { float f; unsigned u; } v; v.f = f;
  unsigned r = v.u + 0x7FFFu + ((v.u >> 16) & 1u);
  return (short)(r >> 16);
}

// ---------------- kernel 1: QKV + ts + Kp (R8-proven body, ones removed) ----------------
// grid: 2(b) x 3(which) x 64(n-tile of 64) = 384 blocks; 256 thr = 4 waves, wave = head.
__global__ __launch_bounds__(256) void qkv_kernel(
    const float* __restrict__ x, const float* __restrict__ tpm,
    const float* __restrict__ qkv_w, const float* __restrict__ qkv_b,
    const float* __restrict__ temperature,
    short* __restrict__ Q, short* __restrict__ K, short* __restrict__ Kp,
    short* __restrict__ V, float* __restrict__ ts) {
  __shared__ float xs[64][64];  // [c][n] 16 KB
  int bid = blockIdx.x;
  int nt = bid % 64;
  int which = (bid / 64) % 3;
  int b = bid / 192;
  int t = threadIdx.x;
  int nl = t & 63;
  int h = __builtin_amdgcn_readfirstlane(t >> 6);  // wave-uniform head
  int n0 = nt * 64;
  int n = n0 + nl;

  {
    int c0 = t >> 6;
    const float* xb = x + ((size_t)b * 64) * NN + n0;
#pragma unroll
    for (int k = 0; k < 16; ++k) {
      int c = c0 + 4 * k;
      xs[c][nl] = xb[(size_t)c * NN + nl];
    }
  }
  __syncthreads();

  int obase = which * 64 + h * 16;
  float acc[16];
#pragma unroll
  for (int d = 0; d < 16; ++d) acc[d] = qkv_b[obase + d];

#pragma unroll 1
  for (int cb = 0; cb < 64; cb += 8) {
    float xr[8];
#pragma unroll
    for (int cc = 0; cc < 8; ++cc) xr[cc] = xs[cb + cc][nl];
#pragma unroll
    for (int d = 0; d < 16; ++d) {
#pragma unroll
      for (int cc = 0; cc < 8; ++cc)
        acc[d] += qkv_w[(obase + d) * 64 + cb + cc] * xr[cc];
    }
  }

  if (which == 2) {
    // V layout: [b][h][d][n]
#pragma unroll
    for (int d = 0; d < 16; ++d)
      V[(((size_t)b * NH + h) * HD + d) * NN + n] = f2bf(acc[d]);
    if (h == 0) {
      float tc = temperature[0];
      tc = fminf(fmaxf(tc, 0.1f), 2.0f);
      float tp = tpm[(size_t)b * NN + n];
      tp = fminf(fmaxf(tp, 0.01f), 1.0f);
      // 0.5 * scale(0.25) * clip(temp) * clip(tpm) * log2(e)
      ts[(size_t)b * NN + n] = 0.125f * tc * tp * 1.44269504088896341f;
    }
  } else if (which == 0) {
    short pk[16];
#pragma unroll
    for (int d = 0; d < 16; ++d) pk[d] = f2bf(acc[d]);
    short* dst = Q + (((size_t)b * NH + h) * NN + n) * HD;
    *(bf16x8_t*)dst = *(bf16x8_t*)&pk[0];
    *(bf16x8_t*)(dst + 8) = *(bf16x8_t*)&pk[8];
  } else {
    // K and Kp = K * ts[n]  (single K-side prescale: R8-proven precision)
    float tc = temperature[0];
    tc = fminf(fmaxf(tc, 0.1f), 2.0f);
    float tp = tpm[(size_t)b * NN + n];
    tp = fminf(fmaxf(tp, 0.01f), 1.0f);
    float tsn = 0.125f * tc * tp * 1.44269504088896341f;
    short pk[16], pkp[16];
#pragma unroll
    for (int d = 0; d < 16; ++d) { pk[d] = f2bf(acc[d]); pkp[d] = f2bf(acc[d] * tsn); }
    short* dst = K + (((size_t)b * NH + h) * NN + n) * HD;
    *(bf16x8_t*)dst = *(bf16x8_t*)&pk[0];
    *(bf16x8_t*)(dst + 8) = *(bf16x8_t*)&pk[8];
    short* dstp = Kp + (((size_t)b * NH + h) * NN + n) * HD;
    *(bf16x8_t*)dstp = *(bf16x8_t*)&pkp[0];
    *(bf16x8_t*)(dstp + 8) = *(bf16x8_t*)&pkp[8];
  }
}

// ---------------- kernel 2: flash attention, 16x16x32 K-dim-packed, low-VGPR ----------------
// Wave = 16 queries. QK: A = [K|Kp] packed along K-dim; Bs=[Q|0], Bsp=[0|Q] ->
// s,sp as f32x4 pairs; arg = fma(s, tsi_f32, sp) (R8 math exactly).
// PV: P stays in-lane (k-permutation shared between A2 pack order and V frag order).
// grid: SK * 8(bh) * 64(qtile of 64) ; block 256 = 4 waves ; 8 waves/SIMD target.
template <int JC>
__global__ __launch_bounds__(256, 8) void attn_kernel_t(
    const short* __restrict__ Q, const short* __restrict__ K, const short* __restrict__ Kp,
    const short* __restrict__ V, const float* __restrict__ ts,
    float* __restrict__ OP, float* __restrict__ LP) {
  int bid = blockIdx.x;
  int tile = bid & 63;
  int bh = (bid >> 6) & 7;
  int seg = bid >> 9;
  int b = bh >> 2, h = bh & 3;

  int tid = threadIdx.x;
  int w = tid >> 6;
  int lane = tid & 63;
  int c = lane & 15;   // query col (QK) / out d col (PV)
  int g = lane >> 4;   // k-slot group

  int qi0 = tile * 64 + w * 16;
  const short* Qb  = Q  + (((size_t)b * NH + h) * NN) * HD;
  const short* Kb  = K  + (((size_t)b * NH + h) * NN) * HD;
  const short* Kpb = Kp + (((size_t)b * NH + h) * NN) * HD;
  const short* Vb  = V  + (((size_t)b * NH + h) * HD) * NN;

  float tsi = ts[(size_t)b * NN + qi0 + c];

  // Q fragment (loop-invariant): lane loads Q[q][ (g&1)*8 .. +8 ); zero-pad per variant
  bf16x8_t qv = *(const bf16x8_t*)(Qb + (size_t)(qi0 + c) * HD + (g & 1) * 8);
  bf16x8_t zero8 = {0, 0, 0, 0, 0, 0, 0, 0};
  bf16x8_t Bs, Bsp;
  if (g < 2) { Bs = qv; Bsp = zero8; } else { Bs = zero8; Bsp = qv; }

  int jbase = seg * JC;
  // A (keys) base: lanes g<2 read K, g>=2 read Kp; d-offset (g&1)*8
  const short* kbase = ((g < 2) ? Kb : Kpb) + (size_t)(jbase + c) * HD + (g & 1) * 8;
  // V base: lane reads d=c row, j-quads at 4g and 16+4g (matches A2 pack order)
  const short* vbase = Vb + (size_t)c * NN + jbase + 4 * g;

  f32x4_t acc = {0.f, 0.f, 0.f, 0.f};
  float dsum = 0.f;
  const f32x4_t z4 = {0.f, 0.f, 0.f, 0.f};

#pragma unroll 1
  for (int jj = 0; jj < JC; jj += 32) {
    bf16x8_t a0 = *(const bf16x8_t*)(kbase + (size_t)jj * HD);          // keys jj+0..15 (row=c)
    bf16x8_t a1 = *(const bf16x8_t*)(kbase + (size_t)(jj + 16) * HD);   // keys jj+16..31
    f32x4_t s0  = __builtin_amdgcn_mfma_f32_16x16x32_bf16(a0, Bs,  z4, 0, 0, 0);
    f32x4_t sp0 = __builtin_amdgcn_mfma_f32_16x16x32_bf16(a0, Bsp, z4, 0, 0, 0);
    f32x4_t s1  = __builtin_amdgcn_mfma_f32_16x16x32_bf16(a1, Bs,  z4, 0, 0, 0);
    f32x4_t sp1 = __builtin_amdgcn_mfma_f32_16x16x32_bf16(a1, Bsp, z4, 0, 0, 0);

    // D: lane (g,c): s*[r] = S(j = jj + 16a + 4g + r, q = qi0 + c)
    float p0[4], p1[4];
#pragma unroll
    for (int r = 0; r < 4; ++r) {
      p0[r] = __builtin_amdgcn_exp2f(fmaf(s0[r], tsi, sp0[r]));
      p1[r] = __builtin_amdgcn_exp2f(fmaf(s1[r], tsi, sp1[r]));
      dsum += p0[r] + p1[r];
    }

    // A2 pack (in-lane): k-slot e = 8g + 4a + r  ->  j = jj + 16a + 4g + r
    int w0, w1, w2, w3;
    asm("v_cvt_pk_bf16_f32 %0, %1, %2" : "=v"(w0) : "v"(p0[0]), "v"(p0[1]));
    asm("v_cvt_pk_bf16_f32 %0, %1, %2" : "=v"(w1) : "v"(p0[2]), "v"(p0[3]));
    asm("v_cvt_pk_bf16_f32 %0, %1, %2" : "=v"(w2) : "v"(p1[0]), "v"(p1[1]));
    asm("v_cvt_pk_bf16_f32 %0, %1, %2" : "=v"(w3) : "v"(p1[2]), "v"(p1[3]));
    union { i32x4_t i; bf16x8_t b; } A2;
    A2.i = (i32x4_t){w0, w1, w2, w3};

    // V fragment with the SAME j-permutation: e = 4a + r (per g): j = jj+16a+4g+r
    union { short4_t s[2]; bf16x8_t b; } B2;
    B2.s[0] = *(const short4_t*)(vbase + jj);
    B2.s[1] = *(const short4_t*)(vbase + jj + 16);

    acc = __builtin_amdgcn_mfma_f32_16x16x32_bf16(A2.b, B2.b, acc, 0, 0, 0);
  }

  // denominator: sum over the 4 g-groups (same c)
  dsum += __shfl_xor(dsum, 16);
  dsum += __shfl_xor(dsum, 32);

  // D2: lane (g,c): out(q = qi0 + 4g + r, d = c)
  float* OPb = OP + ((((size_t)seg * 2 + b) * NH + h) * HD) * NN;
  float* LPb = LP + (((size_t)seg * 2 + b) * NH + h) * NN;
  *(f32x4_t*)(OPb + (size_t)c * NN + qi0 + 4 * g) = acc;
  if (g == 0) LPb[qi0 + c] = dsum;
}

// ---------------- kernel 3: merge partials + proj (compile-time SK; R8-proven) ----------------
template <int SK>
__global__ __launch_bounds__(256) void proj_kernel_t(
    const float* __restrict__ OP, const float* __restrict__ LP,
    const float* __restrict__ proj_w, const float* __restrict__ proj_b,
    float* __restrict__ out) {
  __shared__ float pv[64][32];
  int bid = blockIdx.x;
  int b = bid >> 7;
  int n0 = (bid & 127) << 5;
  int t = threadIdx.x;
  int nl = t & 31;
  int g = t >> 5;  // 0..7
  int n = n0 + nl;
  int h = g >> 1;

  float lpv[SK];
#pragma unroll
  for (int s = 0; s < SK; ++s)
    lpv[s] = LP[(((size_t)s * 2 + b) * NH + h) * NN + n];
  float opv[8][SK];
#pragma unroll
  for (int cc = 0; cc < 8; ++cc) {
    int d = (g * 8 + cc) & 15;
#pragma unroll
    for (int s = 0; s < SK; ++s)
      opv[cc][s] = OP[((((size_t)s * 2 + b) * NH + h) * HD + d) * NN + n];
  }
  float ls = 0.f;
#pragma unroll
  for (int s = 0; s < SK; ++s) ls += lpv[s];
  float inv = 1.0f / ls;
#pragma unroll
  for (int cc = 0; cc < 8; ++cc) {
    float a = 0.f;
#pragma unroll
    for (int s = 0; s < SK; ++s) a += opv[cc][s];
    pv[g * 8 + cc][nl] = a * inv;
  }
  __syncthreads();

#pragma unroll
  for (int oo = 0; oo < 8; ++oo) {
    int o = g * 8 + oo;
    float a = proj_b[o];
#pragma unroll
    for (int c = 0; c < 64; ++c) a += proj_w[o * 64 + c] * pv[c][nl];
    out[((size_t)b * CC + o) * NN + n] = a;
  }
}

extern "C" void kernel_launch(void* const* d_in, const int* in_sizes, int n_in,
                              void* d_out, int out_size, void* d_ws, size_t ws_size,
                              hipStream_t stream) {
  const float* x = (const float*)d_in[0];
  const float* tpm = (const float*)d_in[1];
  const float* qkv_w = (const float*)d_in[2];
  const float* qkv_b = (const float*)d_in[3];
  const float* proj_w = (const float*)d_in[4];
  const float* proj_b = (const float*)d_in[5];
  const float* temperature = (const float*)d_in[6];
  float* out = (float*)d_out;

  const size_t MB = 1u << 20;
  char* ws = (char*)d_ws;
  short* Q  = (short*)(ws);
  short* K  = (short*)(ws + 1 * MB);
  short* Kp = (short*)(ws + 2 * MB);
  short* V  = (short*)(ws + 3 * MB);
  float* ts = (float*)(ws + 4 * MB);            // 32 KB
  size_t lp_off = 4 * MB + 32768;

  int SK = 1;
  for (int cand = 4; cand >= 1; cand >>= 1) {
    size_t need = lp_off + (size_t)cand * (128 * 1024) + (size_t)cand * (2 * MB);
    if (ws_size >= need) { SK = cand; break; }
  }
  float* LP = (float*)(ws + lp_off);
  float* OP = (float*)(ws + lp_off + (size_t)SK * 128 * 1024);

  qkv_kernel<<<2 * 3 * 64, 256, 0, stream>>>(x, tpm, qkv_w, qkv_b, temperature, Q, K, Kp, V, ts);
  if (SK == 4)      attn_kernel_t<1024><<<4 * 512, 256, 0, stream>>>(Q, K, Kp, V, ts, OP, LP);
  else if (SK == 2) attn_kernel_t<2048><<<2 * 512, 256, 0, stream>>>(Q, K, Kp, V, ts, OP, LP);
  else              attn_kernel_t<4096><<<1 * 512, 256, 0, stream>>>(Q, K, Kp, V, ts, OP, LP);
  if (SK == 4)      proj_kernel_t<4><<<2 * 128, 256, 0, stream>>>(OP, LP, proj_w, proj_b, out);
  else if (SK == 2) proj_kernel_t<2><<<2 * 128, 256, 0, stream>>>(OP, LP, proj_w, proj_b, out);
  else              proj_kernel_t<1><<<2 * 128, 256, 0, stream>>>(OP, LP, proj_w, proj_b, out);
}

// Round 12
// 68.762 us; speedup vs baseline: 2.3664x; 1.4855x over previous
//
#include <hip/hip_runtime.h>
#include <hip/hip_bf16.h>
#include <math.h>

typedef __attribute__((ext_vector_type(8))) short bf16x8_t;
typedef __attribute__((ext_vector_type(4))) int i32x4_t;
typedef __attribute__((ext_vector_type(2))) int i32x2_t;
typedef __attribute__((ext_vector_type(4))) float f32x4_t;
typedef __attribute__((ext_vector_type(16))) float f32x16_t;

#define NH 4
#define HD 16
#define NN 4096
#define CC 64

__device__ __forceinline__ short f2bf(float f) {
  union { float f; unsigned u; } v; v.f = f;
  unsigned r = v.u + 0x7FFFu + ((v.u >> 16) & 1u);
  return (short)(r >> 16);
}

// ---------------- kernel 1: QKV + ts + Kp + ones (R8-proven) ----------------
__global__ __launch_bounds__(256) void qkv_kernel(
    const float* __restrict__ x, const float* __restrict__ tpm,
    const float* __restrict__ qkv_w, const float* __restrict__ qkv_b,
    const float* __restrict__ temperature,
    short* __restrict__ Q, short* __restrict__ K, short* __restrict__ Kp,
    short* __restrict__ V, float* __restrict__ ts, short* __restrict__ ones) {
  __shared__ float xs[64][64];  // [c][n] 16 KB
  int bid = blockIdx.x;
  if (bid < 17) {
    int idx = bid * 256 + threadIdx.x;
    if (idx < 4352) ones[idx] = (short)0x3F80;
  }
  int nt = bid % 64;
  int which = (bid / 64) % 3;
  int b = bid / 192;
  int t = threadIdx.x;
  int nl = t & 63;
  int h = __builtin_amdgcn_readfirstlane(t >> 6);  // wave-uniform head
  int n0 = nt * 64;
  int n = n0 + nl;

  {
    int c0 = t >> 6;
    const float* xb = x + ((size_t)b * 64) * NN + n0;
#pragma unroll
    for (int k = 0; k < 16; ++k) {
      int c = c0 + 4 * k;
      xs[c][nl] = xb[(size_t)c * NN + nl];
    }
  }
  __syncthreads();

  int obase = which * 64 + h * 16;
  float acc[16];
#pragma unroll
  for (int d = 0; d < 16; ++d) acc[d] = qkv_b[obase + d];

#pragma unroll 1
  for (int cb = 0; cb < 64; cb += 8) {
    float xr[8];
#pragma unroll
    for (int cc = 0; cc < 8; ++cc) xr[cc] = xs[cb + cc][nl];
#pragma unroll
    for (int d = 0; d < 16; ++d) {
#pragma unroll
      for (int cc = 0; cc < 8; ++cc)
        acc[d] += qkv_w[(obase + d) * 64 + cb + cc] * xr[cc];
    }
  }

  if (which == 2) {
#pragma unroll
    for (int d = 0; d < 16; ++d)
      V[(((size_t)b * NH + h) * HD + d) * NN + n] = f2bf(acc[d]);
    if (h == 0) {
      float tc = temperature[0];
      tc = fminf(fmaxf(tc, 0.1f), 2.0f);
      float tp = tpm[(size_t)b * NN + n];
      tp = fminf(fmaxf(tp, 0.01f), 1.0f);
      ts[(size_t)b * NN + n] = 0.125f * tc * tp * 1.44269504088896341f;
    }
  } else if (which == 0) {
    short pk[16];
#pragma unroll
    for (int d = 0; d < 16; ++d) pk[d] = f2bf(acc[d]);
    short* dst = Q + (((size_t)b * NH + h) * NN + n) * HD;
    *(bf16x8_t*)dst = *(bf16x8_t*)&pk[0];
    *(bf16x8_t*)(dst + 8) = *(bf16x8_t*)&pk[8];
  } else {
    float tc = temperature[0];
    tc = fminf(fmaxf(tc, 0.1f), 2.0f);
    float tp = tpm[(size_t)b * NN + n];
    tp = fminf(fmaxf(tp, 0.01f), 1.0f);
    float tsn = 0.125f * tc * tp * 1.44269504088896341f;
    short pk[16], pkp[16];
#pragma unroll
    for (int d = 0; d < 16; ++d) { pk[d] = f2bf(acc[d]); pkp[d] = f2bf(acc[d] * tsn); }
    short* dst = K + (((size_t)b * NH + h) * NN + n) * HD;
    *(bf16x8_t*)dst = *(bf16x8_t*)&pk[0];
    *(bf16x8_t*)(dst + 8) = *(bf16x8_t*)&pk[8];
    short* dstp = Kp + (((size_t)b * NH + h) * NN + n) * HD;
    *(bf16x8_t*)dstp = *(bf16x8_t*)&pkp[0];
    *(bf16x8_t*)(dstp + 8) = *(bf16x8_t*)&pkp[8];
  }
}

// ---------------- kernel 2: flash attention (R8 body, byte-identical math) ----------------
// grid: SK * 8(bh) * 32(qtile); block 256 = 4 waves, each wave owns 32 q.
__global__ __launch_bounds__(256, 4) void attn_kernel(
    const short* __restrict__ Q, const short* __restrict__ K, const short* __restrict__ Kp,
    const short* __restrict__ V, const short* __restrict__ ones, const float* __restrict__ ts,
    float* __restrict__ OP, float* __restrict__ LP, int jcount) {
  int bid = blockIdx.x;
  int tile = bid & 31;
  int bh = (bid >> 5) & 7;
  int seg = bid >> 8;
  int b = bh >> 2, h = bh & 3;

  int tid = threadIdx.x;
  int w = tid >> 6;
  int lane = tid & 63;
  int half = lane >> 5;
  int l31 = lane & 31;

  int qi0 = tile * 128 + w * 32;
  const short* Qb = Q + (((size_t)b * NH + h) * NN) * HD;
  const short* Kb = K + (((size_t)b * NH + h) * NN) * HD;
  const short* Kpb = Kp + (((size_t)b * NH + h) * NN) * HD;
  const short* Vb = V + (((size_t)b * NH + h) * HD) * NN;

  float tsi = ts[(size_t)b * NN + qi0 + l31];
  bf16x8_t qf = *(const bf16x8_t*)(Qb + (size_t)(qi0 + l31) * HD + 8 * half);

  int jbase = seg * jcount;
  const short* vrow = (l31 < 16) ? (Vb + (size_t)l31 * NN + jbase) : ones;

  f32x16_t acc = {0.f,0.f,0.f,0.f,0.f,0.f,0.f,0.f,0.f,0.f,0.f,0.f,0.f,0.f,0.f,0.f};
  const f32x16_t z16 = {0.f,0.f,0.f,0.f,0.f,0.f,0.f,0.f,0.f,0.f,0.f,0.f,0.f,0.f,0.f,0.f};

#pragma unroll 4
  for (int jj = 0; jj < jcount; jj += 32) {
    const short* kptr = Kb + (size_t)(jbase + jj + l31) * HD + 8 * half;
    const short* kpptr = Kpb + (size_t)(jbase + jj + l31) * HD + 8 * half;
    bf16x8_t ak = *(const bf16x8_t*)kptr;
    bf16x8_t akp = *(const bf16x8_t*)kpptr;
    f32x16_t s = __builtin_amdgcn_mfma_f32_32x32x16_bf16(ak, qf, z16, 0, 0, 0);
    f32x16_t sp = __builtin_amdgcn_mfma_f32_32x32x16_bf16(akp, qf, z16, 0, 0, 0);

    float p[16];
#pragma unroll
    for (int r = 0; r < 16; ++r)
      p[r] = __builtin_amdgcn_exp2f(s[r] * tsi + sp[r]);

    int wr[8];
#pragma unroll
    for (int m = 0; m < 8; ++m)
      asm("v_cvt_pk_bf16_f32 %0, %1, %2" : "=v"(wr[m]) : "v"(p[2 * m]), "v"(p[2 * m + 1]));

    i32x2_t s02 = __builtin_amdgcn_permlane32_swap(wr[0], wr[2], false, false);
    i32x2_t s13 = __builtin_amdgcn_permlane32_swap(wr[1], wr[3], false, false);
    i32x2_t s46 = __builtin_amdgcn_permlane32_swap(wr[4], wr[6], false, false);
    i32x2_t s57 = __builtin_amdgcn_permlane32_swap(wr[5], wr[7], false, false);
    union { i32x4_t i; bf16x8_t b; } pa0, pa1;
    pa0.i = (i32x4_t){s02[0], s13[0], s02[1], s13[1]};
    pa1.i = (i32x4_t){s46[0], s57[0], s46[1], s57[1]};

    bf16x8_t bv0 = *(const bf16x8_t*)(vrow + jj + 8 * half);
    bf16x8_t bv1 = *(const bf16x8_t*)(vrow + jj + 16 + 8 * half);
    acc = __builtin_amdgcn_mfma_f32_32x32x16_bf16(pa0.b, bv0, acc, 0, 0, 0);
    acc = __builtin_amdgcn_mfma_f32_32x32x16_bf16(pa1.b, bv1, acc, 0, 0, 0);
  }

  float* OPb = OP + ((((size_t)seg * 2 + b) * NH + h) * HD) * NN;
  float* LPb = LP + (((size_t)seg * 2 + b) * NH + h) * NN;
  if (l31 < 16) {
#pragma unroll
    for (int g4 = 0; g4 < 4; ++g4) {
      f32x4_t vv = {acc[4 * g4 + 0], acc[4 * g4 + 1], acc[4 * g4 + 2], acc[4 * g4 + 3]};
      *(f32x4_t*)(OPb + (size_t)l31 * NN + qi0 + 4 * half + 8 * g4) = vv;
    }
  } else if (l31 == 16) {
#pragma unroll
    for (int g4 = 0; g4 < 4; ++g4) {
      f32x4_t vv = {acc[4 * g4 + 0], acc[4 * g4 + 1], acc[4 * g4 + 2], acc[4 * g4 + 3]};
      *(f32x4_t*)(LPb + qi0 + 4 * half + 8 * g4) = vv;
    }
  }
}

// ---------------- kernel 3: merge partials + proj (compile-time SK; R8-proven) ----------------
template <int SK>
__global__ __launch_bounds__(256) void proj_kernel_t(
    const float* __restrict__ OP, const float* __restrict__ LP,
    const float* __restrict__ proj_w, const float* __restrict__ proj_b,
    float* __restrict__ out) {
  __shared__ float pv[64][32];
  int bid = blockIdx.x;
  int b = bid >> 7;
  int n0 = (bid & 127) << 5;
  int t = threadIdx.x;
  int nl = t & 31;
  int g = t >> 5;  // 0..7
  int n = n0 + nl;
  int h = g >> 1;

  float lpv[SK];
#pragma unroll
  for (int s = 0; s < SK; ++s)
    lpv[s] = LP[(((size_t)s * 2 + b) * NH + h) * NN + n];
  float opv[8][SK];
#pragma unroll
  for (int cc = 0; cc < 8; ++cc) {
    int d = (g * 8 + cc) & 15;
#pragma unroll
    for (int s = 0; s < SK; ++s)
      opv[cc][s] = OP[((((size_t)s * 2 + b) * NH + h) * HD + d) * NN + n];
  }
  float ls = 0.f;
#pragma unroll
  for (int s = 0; s < SK; ++s) ls += lpv[s];
  float inv = 1.0f / ls;
#pragma unroll
  for (int cc = 0; cc < 8; ++cc) {
    float a = 0.f;
#pragma unroll
    for (int s = 0; s < SK; ++s) a += opv[cc][s];
    pv[g * 8 + cc][nl] = a * inv;
  }
  __syncthreads();

#pragma unroll
  for (int oo = 0; oo < 8; ++oo) {
    int o = g * 8 + oo;
    float a = proj_b[o];
#pragma unroll
    for (int c = 0; c < 64; ++c) a += proj_w[o * 64 + c] * pv[c][nl];
    out[((size_t)b * CC + o) * NN + n] = a;
  }
}

extern "C" void kernel_launch(void* const* d_in, const int* in_sizes, int n_in,
                              void* d_out, int out_size, void* d_ws, size_t ws_size,
                              hipStream_t stream) {
  const float* x = (const float*)d_in[0];
  const float* tpm = (const float*)d_in[1];
  const float* qkv_w = (const float*)d_in[2];
  const float* qkv_b = (const float*)d_in[3];
  const float* proj_w = (const float*)d_in[4];
  const float* proj_b = (const float*)d_in[5];
  const float* temperature = (const float*)d_in[6];
  float* out = (float*)d_out;

  const size_t MB = 1u << 20;
  char* ws = (char*)d_ws;
  short* Q    = (short*)(ws);
  short* K    = (short*)(ws + 1 * MB);
  short* Kp   = (short*)(ws + 2 * MB);
  short* V    = (short*)(ws + 3 * MB);
  float* ts   = (float*)(ws + 4 * MB);            // 32 KB
  short* ones = (short*)(ws + 4 * MB + 32768);    // 16 KB (4352 shorts used)
  size_t lp_off = 4 * MB + 49152;

  // occupancy lever: SK=8 -> 2048 attn blocks (32 waves/CU offered; VGPR=80 caps ~24/CU)
  int SK = 1;
  for (int cand = 8; cand >= 1; cand >>= 1) {
    size_t need = lp_off + (size_t)cand * (128 * 1024) + (size_t)cand * (2 * MB);
    if (ws_size >= need) { SK = cand; break; }
  }
  float* LP = (float*)(ws + lp_off);
  float* OP = (float*)(ws + lp_off + (size_t)SK * 128 * 1024);

  qkv_kernel<<<2 * 3 * 64, 256, 0, stream>>>(x, tpm, qkv_w, qkv_b, temperature, Q, K, Kp, V, ts, ones);
  attn_kernel<<<SK * 256, 256, 0, stream>>>(Q, K, Kp, V, ones, ts, OP, LP, NN / SK);
  if (SK == 8)      proj_kernel_t<8><<<2 * 128, 256, 0, stream>>>(OP, LP, proj_w, proj_b, out);
  else if (SK == 4) proj_kernel_t<4><<<2 * 128, 256, 0, stream>>>(OP, LP, proj_w, proj_b, out);
  else if (SK == 2) proj_kernel_t<2><<<2 * 128, 256, 0, stream>>>(OP, LP, proj_w, proj_b, out);
  else              proj_kernel_t<1><<<2 * 128, 256, 0, stream>>>(OP, LP, proj_w, proj_b, out);
}

// Round 13
// 57.272 us; speedup vs baseline: 2.8411x; 1.2006x over previous
//
#include <hip/hip_runtime.h>
#include <hip/hip_bf16.h>
#include <math.h>

typedef __attribute__((ext_vector_type(8))) short bf16x8_t;
typedef __attribute__((ext_vector_type(4))) int i32x4_t;
typedef __attribute__((ext_vector_type(2))) int i32x2_t;
typedef __attribute__((ext_vector_type(2))) float f32x2_t;
typedef __attribute__((ext_vector_type(4))) float f32x4_t;
typedef __attribute__((ext_vector_type(16))) float f32x16_t;

#define NH 4
#define HD 16
#define NN 4096
#define CC 64

__device__ __forceinline__ short f2bf(float f) {
  union { float f; unsigned u; } v; v.f = f;
  unsigned r = v.u + 0x7FFFu + ((v.u >> 16) & 1u);
  return (short)(r >> 16);
}

// ---------------- kernel 1: QKV + ts + Kp + ones (R8-proven) ----------------
__global__ __launch_bounds__(256) void qkv_kernel(
    const float* __restrict__ x, const float* __restrict__ tpm,
    const float* __restrict__ qkv_w, const float* __restrict__ qkv_b,
    const float* __restrict__ temperature,
    short* __restrict__ Q, short* __restrict__ K, short* __restrict__ Kp,
    short* __restrict__ V, float* __restrict__ ts, short* __restrict__ ones) {
  __shared__ float xs[64][64];  // [c][n] 16 KB
  int bid = blockIdx.x;
  if (bid < 17) {
    int idx = bid * 256 + threadIdx.x;
    if (idx < 4352) ones[idx] = (short)0x3F80;
  }
  int nt = bid % 64;
  int which = (bid / 64) % 3;
  int b = bid / 192;
  int t = threadIdx.x;
  int nl = t & 63;
  int h = __builtin_amdgcn_readfirstlane(t >> 6);  // wave-uniform head
  int n0 = nt * 64;
  int n = n0 + nl;

  {
    int c0 = t >> 6;
    const float* xb = x + ((size_t)b * 64) * NN + n0;
#pragma unroll
    for (int k = 0; k < 16; ++k) {
      int c = c0 + 4 * k;
      xs[c][nl] = xb[(size_t)c * NN + nl];
    }
  }
  __syncthreads();

  int obase = which * 64 + h * 16;
  float acc[16];
#pragma unroll
  for (int d = 0; d < 16; ++d) acc[d] = qkv_b[obase + d];

#pragma unroll 1
  for (int cb = 0; cb < 64; cb += 8) {
    float xr[8];
#pragma unroll
    for (int cc = 0; cc < 8; ++cc) xr[cc] = xs[cb + cc][nl];
#pragma unroll
    for (int d = 0; d < 16; ++d) {
#pragma unroll
      for (int cc = 0; cc < 8; ++cc)
        acc[d] += qkv_w[(obase + d) * 64 + cb + cc] * xr[cc];
    }
  }

  if (which == 2) {
#pragma unroll
    for (int d = 0; d < 16; ++d)
      V[(((size_t)b * NH + h) * HD + d) * NN + n] = f2bf(acc[d]);
    if (h == 0) {
      float tc = temperature[0];
      tc = fminf(fmaxf(tc, 0.1f), 2.0f);
      float tp = tpm[(size_t)b * NN + n];
      tp = fminf(fmaxf(tp, 0.01f), 1.0f);
      ts[(size_t)b * NN + n] = 0.125f * tc * tp * 1.44269504088896341f;
    }
  } else if (which == 0) {
    short pk[16];
#pragma unroll
    for (int d = 0; d < 16; ++d) pk[d] = f2bf(acc[d]);
    short* dst = Q + (((size_t)b * NH + h) * NN + n) * HD;
    *(bf16x8_t*)dst = *(bf16x8_t*)&pk[0];
    *(bf16x8_t*)(dst + 8) = *(bf16x8_t*)&pk[8];
  } else {
    float tc = temperature[0];
    tc = fminf(fmaxf(tc, 0.1f), 2.0f);
    float tp = tpm[(size_t)b * NN + n];
    tp = fminf(fmaxf(tp, 0.01f), 1.0f);
    float tsn = 0.125f * tc * tp * 1.44269504088896341f;
    short pk[16], pkp[16];
#pragma unroll
    for (int d = 0; d < 16; ++d) { pk[d] = f2bf(acc[d]); pkp[d] = f2bf(acc[d] * tsn); }
    short* dst = K + (((size_t)b * NH + h) * NN + n) * HD;
    *(bf16x8_t*)dst = *(bf16x8_t*)&pk[0];
    *(bf16x8_t*)(dst + 8) = *(bf16x8_t*)&pk[8];
    short* dstp = Kp + (((size_t)b * NH + h) * NN + n) * HD;
    *(bf16x8_t*)dstp = *(bf16x8_t*)&pkp[0];
    *(bf16x8_t*)(dstp + 8) = *(bf16x8_t*)&pkp[8];
  }
}

// ---------------- kernel 2: flash attention (R8 structure; packed-f32 arg, unroll 8) ----------------
// grid: SK * 8(bh) * 32(qtile); block 256 = 4 waves, each wave owns 32 q.
__global__ __launch_bounds__(256, 4) void attn_kernel(
    const short* __restrict__ Q, const short* __restrict__ K, const short* __restrict__ Kp,
    const short* __restrict__ V, const short* __restrict__ ones, const float* __restrict__ ts,
    float* __restrict__ OP, float* __restrict__ LP, int jcount) {
  int bid = blockIdx.x;
  int tile = bid & 31;
  int bh = (bid >> 5) & 7;
  int seg = bid >> 8;
  int b = bh >> 2, h = bh & 3;

  int tid = threadIdx.x;
  int w = tid >> 6;
  int lane = tid & 63;
  int half = lane >> 5;
  int l31 = lane & 31;

  int qi0 = tile * 128 + w * 32;
  const short* Qb = Q + (((size_t)b * NH + h) * NN) * HD;
  const short* Kb = K + (((size_t)b * NH + h) * NN) * HD;
  const short* Kpb = Kp + (((size_t)b * NH + h) * NN) * HD;
  const short* Vb = V + (((size_t)b * NH + h) * HD) * NN;

  float tsi = ts[(size_t)b * NN + qi0 + l31];
  f32x2_t tsi2 = {tsi, tsi};
  bf16x8_t qf = *(const bf16x8_t*)(Qb + (size_t)(qi0 + l31) * HD + 8 * half);

  int jbase = seg * jcount;
  const short* vrow = (l31 < 16) ? (Vb + (size_t)l31 * NN + jbase) : ones;

  f32x16_t acc = {0.f,0.f,0.f,0.f,0.f,0.f,0.f,0.f,0.f,0.f,0.f,0.f,0.f,0.f,0.f,0.f};
  const f32x16_t z16 = {0.f,0.f,0.f,0.f,0.f,0.f,0.f,0.f,0.f,0.f,0.f,0.f,0.f,0.f,0.f,0.f};

#pragma unroll 8
  for (int jj = 0; jj < jcount; jj += 32) {
    const short* kptr = Kb + (size_t)(jbase + jj + l31) * HD + 8 * half;
    const short* kpptr = Kpb + (size_t)(jbase + jj + l31) * HD + 8 * half;
    bf16x8_t ak = *(const bf16x8_t*)kptr;
    bf16x8_t akp = *(const bf16x8_t*)kpptr;
    f32x16_t s = __builtin_amdgcn_mfma_f32_32x32x16_bf16(ak, qf, z16, 0, 0, 0);
    f32x16_t sp = __builtin_amdgcn_mfma_f32_32x32x16_bf16(akp, qf, z16, 0, 0, 0);

    // packed arg = s*tsi + sp on f32 pairs (compiler can emit v_pk_fma_f32),
    // then per-element exp2. Same fma math as R8 — bit-identical results.
    int wr[8];
#pragma unroll
    for (int m = 0; m < 8; ++m) {
      f32x2_t sv = {s[2 * m], s[2 * m + 1]};
      f32x2_t spv = {sp[2 * m], sp[2 * m + 1]};
      f32x2_t argv = sv * tsi2 + spv;
      float p0 = __builtin_amdgcn_exp2f(argv[0]);
      float p1 = __builtin_amdgcn_exp2f(argv[1]);
      asm("v_cvt_pk_bf16_f32 %0, %1, %2" : "=v"(wr[m]) : "v"(p0), "v"(p1));
    }

    i32x2_t s02 = __builtin_amdgcn_permlane32_swap(wr[0], wr[2], false, false);
    i32x2_t s13 = __builtin_amdgcn_permlane32_swap(wr[1], wr[3], false, false);
    i32x2_t s46 = __builtin_amdgcn_permlane32_swap(wr[4], wr[6], false, false);
    i32x2_t s57 = __builtin_amdgcn_permlane32_swap(wr[5], wr[7], false, false);
    union { i32x4_t i; bf16x8_t b; } pa0, pa1;
    pa0.i = (i32x4_t){s02[0], s13[0], s02[1], s13[1]};
    pa1.i = (i32x4_t){s46[0], s57[0], s46[1], s57[1]};

    bf16x8_t bv0 = *(const bf16x8_t*)(vrow + jj + 8 * half);
    bf16x8_t bv1 = *(const bf16x8_t*)(vrow + jj + 16 + 8 * half);
    acc = __builtin_amdgcn_mfma_f32_32x32x16_bf16(pa0.b, bv0, acc, 0, 0, 0);
    acc = __builtin_amdgcn_mfma_f32_32x32x16_bf16(pa1.b, bv1, acc, 0, 0, 0);
  }

  float* OPb = OP + ((((size_t)seg * 2 + b) * NH + h) * HD) * NN;
  float* LPb = LP + (((size_t)seg * 2 + b) * NH + h) * NN;
  if (l31 < 16) {
#pragma unroll
    for (int g4 = 0; g4 < 4; ++g4) {
      f32x4_t vv = {acc[4 * g4 + 0], acc[4 * g4 + 1], acc[4 * g4 + 2], acc[4 * g4 + 3]};
      *(f32x4_t*)(OPb + (size_t)l31 * NN + qi0 + 4 * half + 8 * g4) = vv;
    }
  } else if (l31 == 16) {
#pragma unroll
    for (int g4 = 0; g4 < 4; ++g4) {
      f32x4_t vv = {acc[4 * g4 + 0], acc[4 * g4 + 1], acc[4 * g4 + 2], acc[4 * g4 + 3]};
      *(f32x4_t*)(LPb + qi0 + 4 * half + 8 * g4) = vv;
    }
  }
}

// ---------------- kernel 3: merge partials + proj (compile-time SK; R8-proven) ----------------
template <int SK>
__global__ __launch_bounds__(256) void proj_kernel_t(
    const float* __restrict__ OP, const float* __restrict__ LP,
    const float* __restrict__ proj_w, const float* __restrict__ proj_b,
    float* __restrict__ out) {
  __shared__ float pv[64][32];
  int bid = blockIdx.x;
  int b = bid >> 7;
  int n0 = (bid & 127) << 5;
  int t = threadIdx.x;
  int nl = t & 31;
  int g = t >> 5;  // 0..7
  int n = n0 + nl;
  int h = g >> 1;

  float lpv[SK];
#pragma unroll
  for (int s = 0; s < SK; ++s)
    lpv[s] = LP[(((size_t)s * 2 + b) * NH + h) * NN + n];
  float opv[8][SK];
#pragma unroll
  for (int cc = 0; cc < 8; ++cc) {
    int d = (g * 8 + cc) & 15;
#pragma unroll
    for (int s = 0; s < SK; ++s)
      opv[cc][s] = OP[((((size_t)s * 2 + b) * NH + h) * HD + d) * NN + n];
  }
  float ls = 0.f;
#pragma unroll
  for (int s = 0; s < SK; ++s) ls += lpv[s];
  float inv = 1.0f / ls;
#pragma unroll
  for (int cc = 0; cc < 8; ++cc) {
    float a = 0.f;
#pragma unroll
    for (int s = 0; s < SK; ++s) a += opv[cc][s];
    pv[g * 8 + cc][nl] = a * inv;
  }
  __syncthreads();

#pragma unroll
  for (int oo = 0; oo < 8; ++oo) {
    int o = g * 8 + oo;
    float a = proj_b[o];
#pragma unroll
    for (int c = 0; c < 64; ++c) a += proj_w[o * 64 + c] * pv[c][nl];
    out[((size_t)b * CC + o) * NN + n] = a;
  }
}

extern "C" void kernel_launch(void* const* d_in, const int* in_sizes, int n_in,
                              void* d_out, int out_size, void* d_ws, size_t ws_size,
                              hipStream_t stream) {
  const float* x = (const float*)d_in[0];
  const float* tpm = (const float*)d_in[1];
  const float* qkv_w = (const float*)d_in[2];
  const float* qkv_b = (const float*)d_in[3];
  const float* proj_w = (const float*)d_in[4];
  const float* proj_b = (const float*)d_in[5];
  const float* temperature = (const float*)d_in[6];
  float* out = (float*)d_out;

  const size_t MB = 1u << 20;
  char* ws = (char*)d_ws;
  short* Q    = (short*)(ws);
  short* K    = (short*)(ws + 1 * MB);
  short* Kp   = (short*)(ws + 2 * MB);
  short* V    = (short*)(ws + 3 * MB);
  float* ts   = (float*)(ws + 4 * MB);            // 32 KB
  short* ones = (short*)(ws + 4 * MB + 32768);    // 16 KB (4352 shorts used)
  size_t lp_off = 4 * MB + 49152;

  // SK=4 is the measured optimum (R8); SK=8 regressed (R12) — attn is VALU-bound.
  int SK = 1;
  for (int cand = 4; cand >= 1; cand >>= 1) {
    size_t need = lp_off + (size_t)cand * (128 * 1024) + (size_t)cand * (2 * MB);
    if (ws_size >= need) { SK = cand; break; }
  }
  float* LP = (float*)(ws + lp_off);
  float* OP = (float*)(ws + lp_off + (size_t)SK * 128 * 1024);

  qkv_kernel<<<2 * 3 * 64, 256, 0, stream>>>(x, tpm, qkv_w, qkv_b, temperature, Q, K, Kp, V, ts, ones);
  attn_kernel<<<SK * 256, 256, 0, stream>>>(Q, K, Kp, V, ones, ts, OP, LP, NN / SK);
  if (SK == 4)      proj_kernel_t<4><<<2 * 128, 256, 0, stream>>>(OP, LP, proj_w, proj_b, out);
  else if (SK == 2) proj_kernel_t<2><<<2 * 128, 256, 0, stream>>>(OP, LP, proj_w, proj_b, out);
  else              proj_kernel_t<1><<<2 * 128, 256, 0, stream>>>(OP, LP, proj_w, proj_b, out);
}

// Round 15
// 56.445 us; speedup vs baseline: 2.8828x; 1.0147x over previous
//
#include <hip/hip_runtime.h>
#include <hip/hip_bf16.h>
#include <math.h>

typedef __attribute__((ext_vector_type(8))) short bf16x8_t;
typedef __attribute__((ext_vector_type(4))) int i32x4_t;
typedef __attribute__((ext_vector_type(2))) int i32x2_t;
typedef __attribute__((ext_vector_type(2))) float f32x2_t;
typedef __attribute__((ext_vector_type(4))) float f32x4_t;
typedef __attribute__((ext_vector_type(16))) float f32x16_t;

#define NH 4
#define HD 16
#define NN 4096
#define CC 64

__device__ __forceinline__ short f2bf(float f) {
  union { float f; unsigned u; } v; v.f = f;
  unsigned r = v.u + 0x7FFFu + ((v.u >> 16) & 1u);
  return (short)(r >> 16);
}

// ---------------- kernel 1: QKV + ts + Kp + ones (R8-proven, byte-identical) ----------------
__global__ __launch_bounds__(256) void qkv_kernel(
    const float* __restrict__ x, const float* __restrict__ tpm,
    const float* __restrict__ qkv_w, const float* __restrict__ qkv_b,
    const float* __restrict__ temperature,
    short* __restrict__ Q, short* __restrict__ K, short* __restrict__ Kp,
    short* __restrict__ V, float* __restrict__ ts, short* __restrict__ ones) {
  __shared__ float xs[64][64];  // [c][n] 16 KB
  int bid = blockIdx.x;
  if (bid < 17) {
    int idx = bid * 256 + threadIdx.x;
    if (idx < 4352) ones[idx] = (short)0x3F80;
  }
  int nt = bid % 64;
  int which = (bid / 64) % 3;
  int b = bid / 192;
  int t = threadIdx.x;
  int nl = t & 63;
  int h = __builtin_amdgcn_readfirstlane(t >> 6);  // wave-uniform head
  int n0 = nt * 64;
  int n = n0 + nl;

  {
    int c0 = t >> 6;
    const float* xb = x + ((size_t)b * 64) * NN + n0;
#pragma unroll
    for (int k = 0; k < 16; ++k) {
      int c = c0 + 4 * k;
      xs[c][nl] = xb[(size_t)c * NN + nl];
    }
  }
  __syncthreads();

  int obase = which * 64 + h * 16;
  float acc[16];
#pragma unroll
  for (int d = 0; d < 16; ++d) acc[d] = qkv_b[obase + d];

#pragma unroll 1
  for (int cb = 0; cb < 64; cb += 8) {
    float xr[8];
#pragma unroll
    for (int cc = 0; cc < 8; ++cc) xr[cc] = xs[cb + cc][nl];
#pragma unroll
    for (int d = 0; d < 16; ++d) {
#pragma unroll
      for (int cc = 0; cc < 8; ++cc)
        acc[d] += qkv_w[(obase + d) * 64 + cb + cc] * xr[cc];
    }
  }

  if (which == 2) {
#pragma unroll
    for (int d = 0; d < 16; ++d)
      V[(((size_t)b * NH + h) * HD + d) * NN + n] = f2bf(acc[d]);
    if (h == 0) {
      float tc = temperature[0];
      tc = fminf(fmaxf(tc, 0.1f), 2.0f);
      float tp = tpm[(size_t)b * NN + n];
      tp = fminf(fmaxf(tp, 0.01f), 1.0f);
      ts[(size_t)b * NN + n] = 0.125f * tc * tp * 1.44269504088896341f;
    }
  } else if (which == 0) {
    short pk[16];
#pragma unroll
    for (int d = 0; d < 16; ++d) pk[d] = f2bf(acc[d]);
    short* dst = Q + (((size_t)b * NH + h) * NN + n) * HD;
    *(bf16x8_t*)dst = *(bf16x8_t*)&pk[0];
    *(bf16x8_t*)(dst + 8) = *(bf16x8_t*)&pk[8];
  } else {
    float tc = temperature[0];
    tc = fminf(fmaxf(tc, 0.1f), 2.0f);
    float tp = tpm[(size_t)b * NN + n];
    tp = fminf(fmaxf(tp, 0.01f), 1.0f);
    float tsn = 0.125f * tc * tp * 1.44269504088896341f;
    short pk[16], pkp[16];
#pragma unroll
    for (int d = 0; d < 16; ++d) { pk[d] = f2bf(acc[d]); pkp[d] = f2bf(acc[d] * tsn); }
    short* dst = K + (((size_t)b * NH + h) * NN + n) * HD;
    *(bf16x8_t*)dst = *(bf16x8_t*)&pk[0];
    *(bf16x8_t*)(dst + 8) = *(bf16x8_t*)&pk[8];
    short* dstp = Kp + (((size_t)b * NH + h) * NN + n) * HD;
    *(bf16x8_t*)dstp = *(bf16x8_t*)&pkp[0];
    *(bf16x8_t*)(dstp + 8) = *(bf16x8_t*)&pkp[8];
  }
}

// ---------------- kernel 2: flash attention (EXACT R13 body — setprio removed) ----------------
// grid: SK * 8(bh) * 32(qtile); block 256 = 4 waves, each wave owns 32 q.
__global__ __launch_bounds__(256, 4) void attn_kernel(
    const short* __restrict__ Q, const short* __restrict__ K, const short* __restrict__ Kp,
    const short* __restrict__ V, const short* __restrict__ ones, const float* __restrict__ ts,
    float* __restrict__ OP, float* __restrict__ LP, int jcount) {
  int bid = blockIdx.x;
  int tile = bid & 31;
  int bh = (bid >> 5) & 7;
  int seg = bid >> 8;
  int b = bh >> 2, h = bh & 3;

  int tid = threadIdx.x;
  int w = tid >> 6;
  int lane = tid & 63;
  int half = lane >> 5;
  int l31 = lane & 31;

  int qi0 = tile * 128 + w * 32;
  const short* Qb = Q + (((size_t)b * NH + h) * NN) * HD;
  const short* Kb = K + (((size_t)b * NH + h) * NN) * HD;
  const short* Kpb = Kp + (((size_t)b * NH + h) * NN) * HD;
  const short* Vb = V + (((size_t)b * NH + h) * HD) * NN;

  float tsi = ts[(size_t)b * NN + qi0 + l31];
  f32x2_t tsi2 = {tsi, tsi};
  bf16x8_t qf = *(const bf16x8_t*)(Qb + (size_t)(qi0 + l31) * HD + 8 * half);

  int jbase = seg * jcount;
  const short* vrow = (l31 < 16) ? (Vb + (size_t)l31 * NN + jbase) : ones;

  f32x16_t acc = {0.f,0.f,0.f,0.f,0.f,0.f,0.f,0.f,0.f,0.f,0.f,0.f,0.f,0.f,0.f,0.f};
  const f32x16_t z16 = {0.f,0.f,0.f,0.f,0.f,0.f,0.f,0.f,0.f,0.f,0.f,0.f,0.f,0.f,0.f,0.f};

#pragma unroll 8
  for (int jj = 0; jj < jcount; jj += 32) {
    const short* kptr = Kb + (size_t)(jbase + jj + l31) * HD + 8 * half;
    const short* kpptr = Kpb + (size_t)(jbase + jj + l31) * HD + 8 * half;
    bf16x8_t ak = *(const bf16x8_t*)kptr;
    bf16x8_t akp = *(const bf16x8_t*)kpptr;
    f32x16_t s = __builtin_amdgcn_mfma_f32_32x32x16_bf16(ak, qf, z16, 0, 0, 0);
    f32x16_t sp = __builtin_amdgcn_mfma_f32_32x32x16_bf16(akp, qf, z16, 0, 0, 0);

    // packed arg = s*tsi + sp on f32 pairs, per-element exp2 (R13-proven).
    int wr[8];
#pragma unroll
    for (int m = 0; m < 8; ++m) {
      f32x2_t sv = {s[2 * m], s[2 * m + 1]};
      f32x2_t spv = {sp[2 * m], sp[2 * m + 1]};
      f32x2_t argv = sv * tsi2 + spv;
      float p0 = __builtin_amdgcn_exp2f(argv[0]);
      float p1 = __builtin_amdgcn_exp2f(argv[1]);
      asm("v_cvt_pk_bf16_f32 %0, %1, %2" : "=v"(wr[m]) : "v"(p0), "v"(p1));
    }

    i32x2_t s02 = __builtin_amdgcn_permlane32_swap(wr[0], wr[2], false, false);
    i32x2_t s13 = __builtin_amdgcn_permlane32_swap(wr[1], wr[3], false, false);
    i32x2_t s46 = __builtin_amdgcn_permlane32_swap(wr[4], wr[6], false, false);
    i32x2_t s57 = __builtin_amdgcn_permlane32_swap(wr[5], wr[7], false, false);
    union { i32x4_t i; bf16x8_t b; } pa0, pa1;
    pa0.i = (i32x4_t){s02[0], s13[0], s02[1], s13[1]};
    pa1.i = (i32x4_t){s46[0], s57[0], s46[1], s57[1]};

    bf16x8_t bv0 = *(const bf16x8_t*)(vrow + jj + 8 * half);
    bf16x8_t bv1 = *(const bf16x8_t*)(vrow + jj + 16 + 8 * half);
    acc = __builtin_amdgcn_mfma_f32_32x32x16_bf16(pa0.b, bv0, acc, 0, 0, 0);
    acc = __builtin_amdgcn_mfma_f32_32x32x16_bf16(pa1.b, bv1, acc, 0, 0, 0);
  }

  float* OPb = OP + ((((size_t)seg * 2 + b) * NH + h) * HD) * NN;
  float* LPb = LP + (((size_t)seg * 2 + b) * NH + h) * NN;
  if (l31 < 16) {
#pragma unroll
    for (int g4 = 0; g4 < 4; ++g4) {
      f32x4_t vv = {acc[4 * g4 + 0], acc[4 * g4 + 1], acc[4 * g4 + 2], acc[4 * g4 + 3]};
      *(f32x4_t*)(OPb + (size_t)l31 * NN + qi0 + 4 * half + 8 * g4) = vv;
    }
  } else if (l31 == 16) {
#pragma unroll
    for (int g4 = 0; g4 < 4; ++g4) {
      f32x4_t vv = {acc[4 * g4 + 0], acc[4 * g4 + 1], acc[4 * g4 + 2], acc[4 * g4 + 3]};
      *(f32x4_t*)(LPb + qi0 + 4 * half + 8 * g4) = vv;
    }
  }
}

// ---------------- kernel 3: merge + proj — 1024 blocks x 8 n-cols (4 blocks/CU) ----------------
template <int SK>
__global__ __launch_bounds__(256) void proj_kernel_t(
    const float* __restrict__ OP, const float* __restrict__ LP,
    const float* __restrict__ proj_w, const float* __restrict__ proj_b,
    float* __restrict__ out) {
  __shared__ float pv[64][8];  // 2 KB
  int bid = blockIdx.x;        // 2(b) * 512 n-tiles of 8
  int b = bid >> 9;
  int n0 = (bid & 511) << 3;
  int t = threadIdx.x;
  int nl = t & 7;
  int g = t >> 3;              // 0..31, owns channels 2g, 2g+1
  int n = n0 + nl;
  int h = g >> 3;              // == (2g+cc)>>4 for cc in {0,1}

  float lpv[SK];
#pragma unroll
  for (int s = 0; s < SK; ++s)
    lpv[s] = LP[(((size_t)s * 2 + b) * NH + h) * NN + n];
  float opv[2][SK];
#pragma unroll
  for (int cc = 0; cc < 2; ++cc) {
    int d = (2 * g + cc) & 15;
#pragma unroll
    for (int s = 0; s < SK; ++s)
      opv[cc][s] = OP[((((size_t)s * 2 + b) * NH + h) * HD + d) * NN + n];
  }
  float ls = 0.f;
#pragma unroll
  for (int s = 0; s < SK; ++s) ls += lpv[s];
  float inv = 1.0f / ls;
#pragma unroll
  for (int cc = 0; cc < 2; ++cc) {
    float a = 0.f;
#pragma unroll
    for (int s = 0; s < SK; ++s) a += opv[cc][s];
    pv[2 * g + cc][nl] = a * inv;
  }
  __syncthreads();

#pragma unroll
  for (int oo = 0; oo < 2; ++oo) {
    int o = 2 * g + oo;
    float a = proj_b[o];
#pragma unroll
    for (int c = 0; c < 64; ++c) a += proj_w[o * 64 + c] * pv[c][nl];
    out[((size_t)b * CC + o) * NN + n] = a;
  }
}

extern "C" void kernel_launch(void* const* d_in, const int* in_sizes, int n_in,
                              void* d_out, int out_size, void* d_ws, size_t ws_size,
                              hipStream_t stream) {
  const float* x = (const float*)d_in[0];
  const float* tpm = (const float*)d_in[1];
  const float* qkv_w = (const float*)d_in[2];
  const float* qkv_b = (const float*)d_in[3];
  const float* proj_w = (const float*)d_in[4];
  const float* proj_b = (const float*)d_in[5];
  const float* temperature = (const float*)d_in[6];
  float* out = (float*)d_out;

  const size_t MB = 1u << 20;
  char* ws = (char*)d_ws;
  short* Q    = (short*)(ws);
  short* K    = (short*)(ws + 1 * MB);
  short* Kp   = (short*)(ws + 2 * MB);
  short* V    = (short*)(ws + 3 * MB);
  float* ts   = (float*)(ws + 4 * MB);            // 32 KB
  short* ones = (short*)(ws + 4 * MB + 32768);    // 16 KB (4352 shorts used)
  size_t lp_off = 4 * MB + 49152;

  // SK=4 is the measured optimum (R8/R12).
  int SK = 1;
  for (int cand = 4; cand >= 1; cand >>= 1) {
    size_t need = lp_off + (size_t)cand * (128 * 1024) + (size_t)cand * (2 * MB);
    if (ws_size >= need) { SK = cand; break; }
  }
  float* LP = (float*)(ws + lp_off);
  float* OP = (float*)(ws + lp_off + (size_t)SK * 128 * 1024);

  qkv_kernel<<<2 * 3 * 64, 256, 0, stream>>>(x, tpm, qkv_w, qkv_b, temperature, Q, K, Kp, V, ts, ones);
  attn_kernel<<<SK * 256, 256, 0, stream>>>(Q, K, Kp, V, ones, ts, OP, LP, NN / SK);
  if (SK == 4)      proj_kernel_t<4><<<2 * 512, 256, 0, stream>>>(OP, LP, proj_w, proj_b, out);
  else if (SK == 2) proj_kernel_t<2><<<2 * 512, 256, 0, stream>>>(OP, LP, proj_w, proj_b, out);
  else              proj_kernel_t<1><<<2 * 512, 256, 0, stream>>>(OP, LP, proj_w, proj_b, out);
}